// Round 3
// baseline (207.189 us; speedup 1.0000x reference)
//
#include <hip/hip_runtime.h>
#include <math.h>

#define D_MELS   80
#define T_DIM    4000
#define NQ       10
#define WS_STR   64            // stride (floats) between ws accumulators: separate cache lines
#define NTHR     256
#define TILE     64            // rows per tile
#define HALO     2
#define ROWS_LDS (TILE + HALO) // 66
#define F4_ROW   20            // float4 per row
#define F4_TILE  (ROWS_LDS * F4_ROW) // 1320
#define NBLK     2000

// ws[q*WS_STR]: 0=l1 1=band 2=diff2 3=tgt2 4=energy 5=mask 6=delta 7=dmask 8=delta2 9=d2mask

__global__ __launch_bounds__(NTHR) void mel_loss_main(
    const float* __restrict__ pred, const float* __restrict__ tgt,
    const float* __restrict__ mask, const float* __restrict__ w,
    float* __restrict__ ws, int BT)
{
    const int tid = threadIdx.x;
    const float4* p4 = (const float4*)pred;
    const float4* q4 = (const float4*)tgt;
    const float4* w4 = (const float4*)w;

    __shared__ float4 eld[F4_TILE];     // 21120 B: e = pred - tgt, 66 rows
    __shared__ float  msk[ROWS_LDS];
    __shared__ float  red[NTHR / 64][NQ];

    float v_l1 = 0.f, v_band = 0.f, v_diff2 = 0.f, v_tgt2 = 0.f, v_energy = 0.f;
    float v_m = 0.f, v_d = 0.f, v_dm = 0.f, v_d2 = 0.f, v_d2m = 0.f;

    for (int base = blockIdx.x * TILE; base < BT; base += gridDim.x * TILE) {
        // ---- mask tile ----
        if (tid < ROWS_LDS) {
            int r = base - HALO + tid;
            msk[tid] = (r >= 0 && r < BT) ? mask[r] : 0.f;
        }

        // ---- phase 1: coalesced load, compute e + pointwise terms ----
        #pragma unroll
        for (int k = 0; k < (F4_TILE + NTHR - 1) / NTHR; ++k) {
            int f = tid + k * NTHR;
            if (f < F4_TILE) {
                int row = base - HALO + f / F4_ROW;
                float4 e = make_float4(0.f, 0.f, 0.f, 0.f);
                if (row >= 0 && row < BT) {
                    int gi = row * F4_ROW + (f % F4_ROW);
                    float4 p = p4[gi];
                    float4 q = q4[gi];
                    e.x = p.x - q.x; e.y = p.y - q.y;
                    e.z = p.z - q.z; e.w = p.w - q.w;
                    if (row >= base) {   // halo rows are accumulated by their own tile
                        float mt = mask[row];
                        float4 wv = w4[f % F4_ROW];
                        float a0 = fabsf(e.x), a1 = fabsf(e.y),
                              a2 = fabsf(e.z), a3 = fabsf(e.w);
                        v_l1    += (a0 + a1 + a2 + a3) * mt;
                        v_band  += (a0 * wv.x + a1 * wv.y + a2 * wv.z + a3 * wv.w) * mt;
                        v_diff2 += (e.x * e.x + e.y * e.y + e.z * e.z + e.w * e.w) * mt;
                        v_tgt2  += (q.x * q.x + q.y * q.y + q.z * q.z + q.w * q.w) * mt;
                    }
                }
                eld[f] = e;
            }
        }
        __syncthreads();

        // ---- phase 2: temporal terms + energy, quad (4 lanes) per row ----
        {
            int rl = tid >> 2;       // 0..63
            int quarter = tid & 3;   // 20-float segment
            int r = base + rl;
            if (r < BT) {
                int t = r % T_DIM;
                float m0 = msk[rl + 2];
                float m1 = (t >= 1) ? msk[rl + 1] : 0.f;
                float m2 = (t >= 2) ? msk[rl] : 0.f;
                float dmv  = m0 * m1;
                float d2mv = dmv * m2;

                const float* ef = (const float*)eld;
                int off0 = (rl + 2) * D_MELS + quarter * 20;

                float dr = 0.f, d2r = 0.f, er = 0.f;
                #pragma unroll
                for (int k = 0; k < 5; ++k) {
                    float4 e0 = *(const float4*)(ef + off0 + 4 * k);
                    float4 e1 = *(const float4*)(ef + off0 - D_MELS + 4 * k);
                    float4 e2 = *(const float4*)(ef + off0 - 2 * D_MELS + 4 * k);
                    er += e0.x + e0.y + e0.z + e0.w;
                    dr += fabsf(e0.x - e1.x) + fabsf(e0.y - e1.y)
                        + fabsf(e0.z - e1.z) + fabsf(e0.w - e1.w);
                    d2r += fabsf(e0.x - 2.f * e1.x + e2.x)
                         + fabsf(e0.y - 2.f * e1.y + e2.y)
                         + fabsf(e0.z - 2.f * e1.z + e2.z)
                         + fabsf(e0.w - 2.f * e1.w + e2.w);
                }
                v_d  += dr * dmv;
                v_d2 += d2r * d2mv;

                er += __shfl_xor(er, 1, 64);
                er += __shfl_xor(er, 2, 64);
                if (quarter == 0) {
                    v_energy += fabsf(er) * m0;
                    v_m   += m0;
                    v_dm  += dmv;
                    v_d2m += d2mv;
                }
            }
        }
        __syncthreads();   // WAR: next iteration overwrites eld/msk
    }

    // ---- final reduction: wave shuffle -> LDS -> strided atomics ----
    float vals[NQ] = {v_l1, v_band, v_diff2, v_tgt2, v_energy,
                      v_m, v_d, v_dm, v_d2, v_d2m};
    #pragma unroll
    for (int q = 0; q < NQ; ++q) {
        float v = vals[q];
        #pragma unroll
        for (int off = 32; off > 0; off >>= 1)
            v += __shfl_down(v, off, 64);
        vals[q] = v;
    }
    int wave = tid >> 6, lane = tid & 63;
    if (lane == 0) {
        #pragma unroll
        for (int q = 0; q < NQ; ++q) red[wave][q] = vals[q];
    }
    __syncthreads();
    if (tid < NQ) {
        float s = 0.f;
        #pragma unroll
        for (int wv = 0; wv < NTHR / 64; ++wv) s += red[wv][tid];
        atomicAdd(&ws[tid * WS_STR], s);
    }
}

__global__ void mel_loss_finalize(const float* __restrict__ ws,
                                  const float* __restrict__ w,
                                  float* __restrict__ out)
{
    if (blockIdx.x == 0 && threadIdx.x == 0) {
        float l1s   = ws[0 * WS_STR], bands = ws[1 * WS_STR];
        float diff2 = ws[2 * WS_STR], tgt2  = ws[3 * WS_STR];
        float energys = ws[4 * WS_STR], ms  = ws[5 * WS_STR];
        float ds    = ws[6 * WS_STR], dms   = ws[7 * WS_STR];
        float d2s   = ws[8 * WS_STR], d2ms  = ws[9 * WS_STR];

        float wsum = 0.f;
        for (int d = 0; d < D_MELS; ++d) wsum += w[d];
        float wmean = wsum / (float)D_MELS;

        float n1  = fmaxf(ms   * (float)D_MELS, 1.f);
        float nd  = fmaxf(dms  * (float)D_MELS, 1.f);
        float nd2 = fmaxf(d2ms * (float)D_MELS, 1.f);

        float l1_loss     = l1s / n1;
        float delta_loss  = ds / nd;
        float delta2_loss = d2s / nd2;
        float sc_num = sqrtf(diff2 / n1);
        float sc_den = fmaxf(sqrtf(tgt2 / n1), 1e-8f);
        float sc_loss = sc_num / sc_den;
        float band_loss = (bands / n1) / wmean;
        float energy_loss = (energys / (float)D_MELS) / fmaxf(ms, 1.f);

        out[0] = 1.0f * l1_loss + 0.5f * delta_loss + 0.25f * delta2_loss
               + 0.5f * sc_loss + 1.0f * band_loss + 0.5f * energy_loss;
    }
}

extern "C" void kernel_launch(void* const* d_in, const int* in_sizes, int n_in,
                              void* d_out, int out_size, void* d_ws, size_t ws_size,
                              hipStream_t stream) {
    const float* pred = (const float*)d_in[0];
    const float* tgt  = (const float*)d_in[1];
    const float* mask = (const float*)d_in[2];
    const float* w    = (const float*)d_in[3];
    int BT = in_sizes[2];          // B*T = 256000
    float* ws = (float*)d_ws;

    hipMemsetAsync(ws, 0, NQ * WS_STR * sizeof(float), stream);

    int tiles = (BT + TILE - 1) / TILE;
    int grid = tiles < NBLK ? tiles : NBLK;
    mel_loss_main<<<grid, NTHR, 0, stream>>>(pred, tgt, mask, w, ws, BT);
    mel_loss_finalize<<<1, 64, 0, stream>>>(ws, w, (float*)d_out);
}

// Round 4
// 193.359 us; speedup vs baseline: 1.0715x; 1.0715x over previous
//
#include <hip/hip_runtime.h>
#include <math.h>

#define D_MELS  80
#define T_DIM   4000
#define F4_ROW  20
#define NQ      10
#define NTHR    256
#define MAXB    1024   // max blocks; partial layout ws[q*MAXB + blk]

// quantities: 0=l1 1=band 2=diff2 3=tgt2 4=energy 5=mask 6=delta 7=dmask 8=delta2 9=d2mask

__global__ __launch_bounds__(NTHR) void mel_loss_main(
    const float* __restrict__ pred, const float* __restrict__ tgt,
    const float* __restrict__ mask, const float* __restrict__ w,
    float* __restrict__ partial, int BT, int nwaves_total)
{
    const int tid  = threadIdx.x;
    const int lane = tid & 63;
    const int qtr  = lane & 3;        // quarter of row (5 float4s)
    const int rw   = lane >> 2;       // row within wave tile (0..15)
    const int gwave = blockIdx.x * (NTHR / 64) + (tid >> 6);

    const float4* p4 = (const float4*)pred;
    const float4* q4 = (const float4*)tgt;

    // band weights for this quarter (registers, L1-resident)
    float4 wv[5];
    #pragma unroll
    for (int k = 0; k < 5; ++k) wv[k] = ((const float4*)w)[qtr + 4 * k];

    float v_l1 = 0.f, v_band = 0.f, v_diff2 = 0.f, v_tgt2 = 0.f, v_energy = 0.f;
    float v_m = 0.f, v_d = 0.f, v_dm = 0.f, v_d2 = 0.f, v_d2m = 0.f;

    const int row_stride = nwaves_total * 16;

    for (int rbase = gwave * 16; rbase < BT; rbase += row_stride) {
        int r = rbase + rw;
        if (r < BT) {
            int t = r % T_DIM;
            bool has1 = (t >= 1);
            bool has2 = (t >= 2);

            const float4* pr0 = p4 + (size_t)r * F4_ROW + qtr;
            const float4* qr0 = q4 + (size_t)r * F4_ROW + qtr;
            const float4* pr1 = has1 ? pr0 - F4_ROW : pr0;
            const float4* qr1 = has1 ? qr0 - F4_ROW : qr0;
            const float4* pr2 = has2 ? pr0 - 2 * F4_ROW : pr0;
            const float4* qr2 = has2 ? qr0 - 2 * F4_ROW : qr0;

            float mt  = mask[r];
            float mt1 = has1 ? mask[r - 1] : 0.f;
            float mt2 = has2 ? mask[r - 2] : 0.f;

            float l1r = 0.f, bandr = 0.f, sqr = 0.f, t2r = 0.f, er = 0.f;
            float dr = 0.f, d2r = 0.f;

            #pragma unroll
            for (int k = 0; k < 5; ++k) {
                float4 p  = pr0[4 * k];
                float4 qq = qr0[4 * k];
                float4 pa = pr1[4 * k];
                float4 qa = qr1[4 * k];
                float4 pb = pr2[4 * k];
                float4 qb = qr2[4 * k];

                float e0 = p.x - qq.x, e1 = p.y - qq.y,
                      e2 = p.z - qq.z, e3 = p.w - qq.w;
                float f0 = pa.x - qa.x, f1 = pa.y - qa.y,
                      f2 = pa.z - qa.z, f3 = pa.w - qa.w;
                float g0 = pb.x - qb.x, g1 = pb.y - qb.y,
                      g2 = pb.z - qb.z, g3 = pb.w - qb.w;

                float a0 = fabsf(e0), a1 = fabsf(e1),
                      a2 = fabsf(e2), a3 = fabsf(e3);

                l1r   += a0 + a1 + a2 + a3;
                bandr += a0 * wv[k].x + a1 * wv[k].y + a2 * wv[k].z + a3 * wv[k].w;
                sqr   += e0 * e0 + e1 * e1 + e2 * e2 + e3 * e3;
                t2r   += qq.x * qq.x + qq.y * qq.y + qq.z * qq.z + qq.w * qq.w;
                er    += e0 + e1 + e2 + e3;
                dr  += fabsf(e0 - f0) + fabsf(e1 - f1)
                     + fabsf(e2 - f2) + fabsf(e3 - f3);
                d2r += fabsf(e0 - 2.f * f0 + g0) + fabsf(e1 - 2.f * f1 + g1)
                     + fabsf(e2 - 2.f * f2 + g2) + fabsf(e3 - 2.f * f3 + g3);
            }

            float dmv  = mt * mt1;
            float d2mv = dmv * mt2;

            v_l1    += l1r * mt;
            v_band  += bandr * mt;
            v_diff2 += sqr * mt;
            v_tgt2  += t2r * mt;
            v_d     += dr * dmv;
            v_d2    += d2r * d2mv;

            // row-sum of e within the quad (lanes r*4 .. r*4+3) — no LDS
            er += __shfl_xor(er, 1, 64);
            er += __shfl_xor(er, 2, 64);
            if (qtr == 0) {
                v_energy += fabsf(er) * mt;
                v_m   += mt;
                v_dm  += dmv;
                v_d2m += d2mv;
            }
        }
    }

    // ---- block reduction: wave shuffle -> LDS -> per-block store (NO atomics) ----
    float vals[NQ] = {v_l1, v_band, v_diff2, v_tgt2, v_energy,
                      v_m, v_d, v_dm, v_d2, v_d2m};
    #pragma unroll
    for (int q = 0; q < NQ; ++q) {
        float v = vals[q];
        #pragma unroll
        for (int off = 32; off > 0; off >>= 1)
            v += __shfl_down(v, off, 64);
        vals[q] = v;
    }
    __shared__ float red[NTHR / 64][NQ];
    int wave = tid >> 6;
    if (lane == 0) {
        #pragma unroll
        for (int q = 0; q < NQ; ++q) red[wave][q] = vals[q];
    }
    __syncthreads();
    if (tid < NQ) {
        float s = 0.f;
        #pragma unroll
        for (int wv2 = 0; wv2 < NTHR / 64; ++wv2) s += red[wv2][tid];
        partial[tid * MAXB + blockIdx.x] = s;
    }
}

__global__ __launch_bounds__(640) void mel_loss_finalize(
    const float* __restrict__ partial, const float* __restrict__ w,
    float* __restrict__ out, int nblk)
{
    const int tid = threadIdx.x;
    const int wv  = tid >> 6;        // quantity index 0..9
    const int lane = tid & 63;
    __shared__ float fin[NQ];

    float s = 0.f;
    for (int i = lane; i < nblk; i += 64) s += partial[wv * MAXB + i];
    #pragma unroll
    for (int off = 32; off > 0; off >>= 1) s += __shfl_down(s, off, 64);
    if (lane == 0) fin[wv] = s;
    __syncthreads();

    if (tid == 0) {
        float l1s = fin[0], bands = fin[1], diff2 = fin[2], tgt2 = fin[3];
        float energys = fin[4], ms = fin[5], ds = fin[6], dms = fin[7];
        float d2s = fin[8], d2ms = fin[9];

        float wsum = 0.f;
        for (int d = 0; d < D_MELS; ++d) wsum += w[d];
        float wmean = wsum / (float)D_MELS;

        float n1  = fmaxf(ms   * (float)D_MELS, 1.f);
        float nd  = fmaxf(dms  * (float)D_MELS, 1.f);
        float nd2 = fmaxf(d2ms * (float)D_MELS, 1.f);

        float l1_loss     = l1s / n1;
        float delta_loss  = ds / nd;
        float delta2_loss = d2s / nd2;
        float sc_num = sqrtf(diff2 / n1);
        float sc_den = fmaxf(sqrtf(tgt2 / n1), 1e-8f);
        float sc_loss = sc_num / sc_den;
        float band_loss = (bands / n1) / wmean;
        float energy_loss = (energys / (float)D_MELS) / fmaxf(ms, 1.f);

        out[0] = 1.0f * l1_loss + 0.5f * delta_loss + 0.25f * delta2_loss
               + 0.5f * sc_loss + 1.0f * band_loss + 0.5f * energy_loss;
    }
}

extern "C" void kernel_launch(void* const* d_in, const int* in_sizes, int n_in,
                              void* d_out, int out_size, void* d_ws, size_t ws_size,
                              hipStream_t stream) {
    const float* pred = (const float*)d_in[0];
    const float* tgt  = (const float*)d_in[1];
    const float* mask = (const float*)d_in[2];
    const float* w    = (const float*)d_in[3];
    int BT = in_sizes[2];                 // B*T = 256000
    float* partial = (float*)d_ws;        // NQ * MAXB floats

    int rows_per_block = (NTHR / 64) * 16;                  // 64
    int blocks_needed = (BT + rows_per_block - 1) / rows_per_block;
    int grid = blocks_needed < MAXB ? blocks_needed : MAXB;
    int nwaves_total = grid * (NTHR / 64);

    mel_loss_main<<<grid, NTHR, 0, stream>>>(pred, tgt, mask, w, partial, BT, nwaves_total);
    mel_loss_finalize<<<1, 640, 0, stream>>>(partial, w, (float*)d_out, grid);
}